// Round 14
// baseline (51.839 us; speedup 1.0000x reference)
//
#include <hip/hip_runtime.h>

// ConvDatapath: bit-serial crossbar conv with per-chunk ADC quantization.
// (resubmit r12 — prior two rounds died to a wedged container before push)
// k_q: quantize x (392 blocks) and w (8 blocks) exactly once into fragment-
//      layout Xq/Wq in d_ws (conflict-free LDS scratch, b128 copy-out).
// k_d: 1568 blocks x 256 thr; wave = (tile, khalf). Per chunk: batched
//      8 first-MFMAs -> 8 second-MFMAs -> pure-VALU ADC burst (decouples
//      MFMA->VALU hazards). Loads prefetched one chunk ahead. Integer
//      reordering only: bit-exact vs reference.
// Nx = 6272, Ny = 128, K = 576 (5 chunks of 116, padded to 128).

#define KDIM  576
#define NPB   116
#define SSTR  688    // scratch row stride: 43*16 -> b128-aligned, 172 dw % 32 = 12

typedef int i32x4 __attribute__((ext_vector_type(4)));
typedef float f32x4 __attribute__((ext_vector_type(4)));

__device__ __forceinline__ i32x4 slice2b(i32x4 v, int sh) {
    i32x4 r;
    r[0] = (int)(((unsigned)v[0] >> sh) & 0x03030303u);
    r[1] = (int)(((unsigned)v[1] >> sh) & 0x03030303u);
    r[2] = (int)(((unsigned)v[2] >> sh) & 0x03030303u);
    r[3] = (int)(((unsigned)v[3] >> sh) & 0x03030303u);
    return r;
}

// quantize one row spread over a 16-lane group (lane i16 holds k=36*i16..+35,
// k-ordered). Stats via 4-step shuffle (exact); 9 dword-aligned b32 writes,
// col = k + 12*chunk (i.e. chunk*128 + k%116).
__device__ __forceinline__ void quant36(const float (&v)[36], unsigned char* rowp,
                                        int i16, float* sc, float* of,
                                        float* sm_, int sidx)
{
    float mn = v[0], mx = v[0], sm = 0.f;
#pragma unroll
    for (int m = 0; m < 36; m++) { mn = fminf(mn, v[m]); mx = fmaxf(mx, v[m]); sm += v[m]; }
#pragma unroll
    for (int off = 1; off < 16; off <<= 1) {
        mn = fminf(mn, __shfl_xor(mn, off));
        mx = fmaxf(mx, __shfl_xor(mx, off));
        sm += __shfl_xor(sm, off);
    }
    float step = (mx - mn) / 255.0f;
    if (i16 == 0) { sc[sidx] = step; of[sidx] = mn; sm_[sidx] = sm; }
    int k0 = i16 * 36;
#pragma unroll
    for (int d = 0; d < 9; d++) {
        unsigned int dw = 0;
#pragma unroll
        for (int mb = 0; mb < 4; mb++) {
            int q = (int)rintf((v[d * 4 + mb] - mn) / step);
            q = q < 0 ? 0 : (q > 255 ? 255 : q);
            dw |= (unsigned)q << (8 * mb);
        }
        int kd = k0 + d * 4;
        int ch = kd / NPB;
        *(unsigned int*)(rowp + kd + 12 * ch) = dw;
    }
}

// zero the K-pad dwords of scratch row (idx>>4), pad dword (idx&15)
__device__ __forceinline__ void zero_pad_row(unsigned char* scr, int idx) {
    int rl = idx >> 4, dwp = idx & 15;
    int col = dwp < 12 ? (dwp / 3) * 128 + 116 + (dwp % 3) * 4
                       : 624 + (dwp - 12) * 4;
    *(unsigned int*)(scr + rl * SSTR + col) = 0u;
}

// copy 16-row scratch -> linear fragment tile (10,240 B) in global.
__device__ __forceinline__ void copy_out(const unsigned char* scr,
                                         unsigned char* dst, int tid) {
    for (int idx = tid; idx < 640; idx += 256) {
        int u = idx >> 4, rl = idx & 15;
        int dst16 = (u >> 3) * 128 + ((u >> 2) & 1) * 64 + (u & 3) * 16 + rl;
        *(i32x4*)(dst + dst16 * 16) = *(const i32x4*)(scr + rl * SSTR + u * 16);
    }
}

// ---------------- kernel 1: one-time quantization of x and w ----------------
__global__ __launch_bounds__(256) void k_q(
    const float* __restrict__ x, const float* __restrict__ w,
    unsigned char* __restrict__ Xq, unsigned char* __restrict__ Wq,
    float* __restrict__ xscg, float* __restrict__ xofg, float* __restrict__ xsmg,
    float* __restrict__ wscg, float* __restrict__ wofg, float* __restrict__ wsmg)
{
    __shared__ float xs2[64 * 57];                      // [cin][kh*18+c]
    __shared__ __align__(16) unsigned char scr[16 * SSTR];

    int tid = threadIdx.x, wv = tid >> 6, lane = tid & 63;
    int g = lane >> 4, i16 = lane & 15;
    int blk = blockIdx.x;

    if (blk < 392) {
        int b = blk >= 196 ? 1 : 0;
        int pos0 = (blk - 196 * b) * 16;
        const float* xb = x + (size_t)(b * 64) * 3136;
        for (int i = tid; i < 64 * 54; i += 256) {
            int cin = i / 54, rem = i - cin * 54;
            int kh = rem / 18;
            int gg = pos0 + (rem - kh * 18) - 1;
            float vv = 0.f;
            if (gg >= 0 && gg < 3136) {
                int hg = gg / 56, wg = gg - hg * 56;
                int r = hg - 1 + kh;
                if (r >= 0 && r < 56) vv = xb[cin * 3136 + r * 56 + wg];
            }
            xs2[cin * 57 + rem] = vv;
        }
        zero_pad_row(scr, tid);
        __syncthreads();

        int i = wv * 4 + g;               // tile-local row 0..15
        int pos = pos0 + i;
        int w_ = pos - (pos / 56) * 56;
        float v[36];
#pragma unroll
        for (int m = 0; m < 36; m++) {
            int r9 = m % 9, kh = r9 / 3, kw = r9 - kh * 3;
            int cin = i16 * 4 + m / 9;
            int ww = w_ - 1 + kw;
            v[m] = (ww >= 0 && ww < 56) ? xs2[cin * 57 + kh * 18 + i + kw] : 0.f;
        }
        quant36(v, scr + i * SSTR, i16, xscg, xofg, xsmg, blk * 16 + i);
        __syncthreads();

        copy_out(scr, Xq + (size_t)blk * 10240, tid);
    } else {
        int ctile = blk - 392;
        zero_pad_row(scr, tid);
        int rl = wv * 4 + g;              // 0..15
        int row = ctile * 16 + rl;
        const float* wr = w + (size_t)row * KDIM + i16 * 36;
        float v[36];
#pragma unroll
        for (int d = 0; d < 9; d++) {
            f32x4 t = *(const f32x4*)(wr + d * 4);
            v[d*4+0] = t[0]; v[d*4+1] = t[1]; v[d*4+2] = t[2]; v[d*4+3] = t[3];
        }
        quant36(v, scr + rl * SSTR, i16, wscg, wofg, wsmg, row);
        __syncthreads();

        copy_out(scr, Wq + (size_t)ctile * 10240, tid);
    }
}

// ---------------- kernel 2: crossbar MFMA + ADC + dequant ----------------
// one chunk, pipeline-decoupled: 8 indep MFMA -> 8 chained MFMA -> ADC burst.
__device__ __forceinline__ void chunk_batched(i32x4 x0, i32x4 x1,
                                              i32x4 w0, i32x4 w1,
                                              i32x4 (&acc2)[2])
{
    const i32x4 zero = {0, 0, 0, 0};
    i32x4 wsl[4][2];
#pragma unroll
    for (int ws = 0; ws < 4; ws++) {
        wsl[ws][0] = slice2b(w0, 6 - 2 * ws);
        wsl[ws][1] = slice2b(w1, 6 - 2 * ws);
    }
#pragma unroll
    for (int half = 0; half < 2; half++) {
        int is0 = half * 2;
        i32x4 a00 = slice2b(x0, 6 - 2 * is0),       a01 = slice2b(x1, 6 - 2 * is0);
        i32x4 a10 = slice2b(x0, 6 - 2 * (is0 + 1)), a11 = slice2b(x1, 6 - 2 * (is0 + 1));
        i32x4 d[8];
        // 8 independent first-MFMAs (C = 0)
#pragma unroll
        for (int ws = 0; ws < 4; ws++) {
            d[ws]     = __builtin_amdgcn_mfma_i32_16x16x64_i8(wsl[ws][0], a00, zero, 0, 0, 0);
            d[4 + ws] = __builtin_amdgcn_mfma_i32_16x16x64_i8(wsl[ws][0], a10, zero, 0, 0, 0);
        }
        // 8 chained second-MFMAs (dep is >= 8 issue slots old)
#pragma unroll
        for (int ws = 0; ws < 4; ws++) {
            d[ws]     = __builtin_amdgcn_mfma_i32_16x16x64_i8(wsl[ws][1], a01, d[ws], 0, 0, 0);
            d[4 + ws] = __builtin_amdgcn_mfma_i32_16x16x64_i8(wsl[ws][1], a11, d[4 + ws], 0, 0, 0);
        }
        // pure-VALU ADC burst, oldest D first (hazard expired)
#pragma unroll
        for (int q = 0; q < 8; q++) {
            int is = is0 + (q >> 2), ws = q & 3;
            int sh = (6 - 2 * is) + (6 - 2 * ws);
#pragma unroll
            for (int r = 0; r < 4; r++) {
                int z = d[q][r];
                z = z > 1024 ? 1024 : z;                 // ADC clip (z >= 0)
                int t = (z >> 2) & 1;
                int r4 = (z + 1 + t) & ~3;               // round-half-even, mult of 4
                acc2[ws & 1][r] += r4 << sh;             // 2^(ish+wsh), exact int
            }
        }
    }
}

__global__ __launch_bounds__(256) void k_d(
    const unsigned char* __restrict__ Xq, const unsigned char* __restrict__ Wq,
    const float* __restrict__ xscg, const float* __restrict__ xofg,
    const float* __restrict__ xsmg,
    const float* __restrict__ wscg, const float* __restrict__ wofg,
    const float* __restrict__ wsmg, float* __restrict__ out)
{
    __shared__ __align__(16) int pacc[2][64][4];

    int tid = threadIdx.x, wv = tid >> 6, lane = tid & 63;
    int g = lane >> 4, i16 = lane & 15;
    int blk = blockIdx.x;                 // 0..1567
    int ct = blk & 7, rp = blk >> 3;      // rp 0..195
    int tl = wv & 1, khalf = wv >> 1;
    int rtile = rp * 2 + tl;              // 0..391
    const unsigned char* xt = Xq + (size_t)rtile * 10240 + lane * 16;
    const unsigned char* wt = Wq + (size_t)ct * 10240 + lane * 16;

    i32x4 acc2[2] = {{0,0,0,0},{0,0,0,0}};

    if (khalf == 0) {
        // chunks 0,1,2 with one-chunk-ahead prefetch
        i32x4 xa0 = *(const i32x4*)(xt),          xa1 = *(const i32x4*)(xt + 1024);
        i32x4 wa0 = *(const i32x4*)(wt),          wa1 = *(const i32x4*)(wt + 1024);
        i32x4 xb0 = *(const i32x4*)(xt + 2048),   xb1 = *(const i32x4*)(xt + 3072);
        i32x4 wb0 = *(const i32x4*)(wt + 2048),   wb1 = *(const i32x4*)(wt + 3072);
        chunk_batched(xa0, xa1, wa0, wa1, acc2);
        xa0 = *(const i32x4*)(xt + 4096); xa1 = *(const i32x4*)(xt + 5120);
        wa0 = *(const i32x4*)(wt + 4096); wa1 = *(const i32x4*)(wt + 5120);
        chunk_batched(xb0, xb1, wb0, wb1, acc2);
        chunk_batched(xa0, xa1, wa0, wa1, acc2);
    } else {
        // chunks 3,4
        i32x4 xa0 = *(const i32x4*)(xt + 6144),  xa1 = *(const i32x4*)(xt + 7168);
        i32x4 wa0 = *(const i32x4*)(wt + 6144),  wa1 = *(const i32x4*)(wt + 7168);
        i32x4 xb0 = *(const i32x4*)(xt + 8192),  xb1 = *(const i32x4*)(xt + 9216);
        i32x4 wb0 = *(const i32x4*)(wt + 8192),  wb1 = *(const i32x4*)(wt + 9216);
        chunk_batched(xa0, xa1, wa0, wa1, acc2);
        chunk_batched(xb0, xb1, wb0, wb1, acc2);
    }

    i32x4 acc;
#pragma unroll
    for (int r = 0; r < 4; r++) acc[r] = acc2[0][r] + acc2[1][r];   // exact

    if (khalf == 0) *(i32x4*)&pacc[tl][lane][0] = acc;
    __syncthreads();

    if (khalf == 1) {
        i32x4 p = *(const i32x4*)&pacc[tl][lane][0];
#pragma unroll
        for (int r = 0; r < 4; r++) acc[r] += p[r];      // chunk-sum, exact

        // epilogue: D[row = w-row (g*4+r), col = x-row (i16)]; 64B coalesced
        int b = rtile >= 196 ? 1 : 0;
        int xrow = rtile * 16 + i16;
        float xs_ = xscg[xrow], xo = xofg[xrow], xsv = xsmg[xrow];
        int hw = (rtile - 196 * b) * 16 + i16;
#pragma unroll
        for (int r = 0; r < 4; r++) {
            int wrow = ct * 16 + g * 4 + r;
            float tt = ((float)acc[r] * xs_) * wscg[wrow];
            float res = ((tt + xo * wsmg[wrow]) + wofg[wrow] * xsv)
                      - (xo * wofg[wrow]) * 576.0f;
            out[(size_t)(b * 128 + wrow) * 3136 + hw] = res;
        }
    }
}

extern "C" void kernel_launch(void* const* d_in, const int* in_sizes, int n_in,
                              void* d_out, int out_size, void* d_ws, size_t ws_size,
                              hipStream_t stream) {
    const float* x = (const float*)d_in[0];   // [2][64][56][56]
    const float* w = (const float*)d_in[1];   // [128][64][3][3]
    float* out = (float*)d_out;               // [2][128][56][56]

    unsigned char* Xq = (unsigned char*)d_ws;          // 392*10,240 = 4,014,080 B
    unsigned char* Wq = Xq + (size_t)392 * 10240;      // 8*10,240   = 81,920 B
    float* xsc = (float*)(Wq + 8 * 10240);
    float* xof = xsc + 6272;
    float* xsm = xof + 6272;
    float* wsc = xsm + 6272;
    float* wof = wsc + 128;
    float* wsm = wof + 128;

    hipLaunchKernelGGL(k_q, dim3(400), dim3(256), 0, stream,
                       x, w, Xq, Wq, xsc, xof, xsm, wsc, wof, wsm);
    hipLaunchKernelGGL(k_d, dim3(1568), dim3(256), 0, stream,
                       Xq, Wq, xsc, xof, xsm, wsc, wof, wsm, out);
}

// Round 15
// 38.395 us; speedup vs baseline: 1.3501x; 1.3501x over previous
//
#include <hip/hip_runtime.h>

// ConvDatapath: bit-serial crossbar conv with per-chunk ADC quantization.
// k_q: quantize x (392 blocks) and w (8 blocks) exactly once into fragment-
//      layout Xq/Wq in d_ws (conflict-free LDS scratch, b128 copy-out).
// k_d: 1568 blocks x 256 thr; wave = (tile, khalf). Phase D is a COMPACT
//      LOOP (chunk x is; ws unrolled x4) so the hot body (~1 KB) stays
//      I$-resident and is reused — the R6-R14 straight-line bodies were
//      25-60 KB executed once per wave (instruction-fetch bound).
//      Integer math identical to reference: bit-exact.
// Nx = 6272, Ny = 128, K = 576 (5 chunks of 116, padded to 128).

#define KDIM  576
#define NPB   116
#define SSTR  688    // scratch row stride: 43*16 -> b128-aligned, 172 dw % 32 = 12

typedef int i32x4 __attribute__((ext_vector_type(4)));
typedef float f32x4 __attribute__((ext_vector_type(4)));

__device__ __forceinline__ i32x4 slice2b(i32x4 v, int sh) {
    i32x4 r;
    r[0] = (int)(((unsigned)v[0] >> sh) & 0x03030303u);
    r[1] = (int)(((unsigned)v[1] >> sh) & 0x03030303u);
    r[2] = (int)(((unsigned)v[2] >> sh) & 0x03030303u);
    r[3] = (int)(((unsigned)v[3] >> sh) & 0x03030303u);
    return r;
}

// ADC: clip 1024, round-half-even to mult of 4, shift-accumulate (sh uniform)
__device__ __forceinline__ void adc4(const i32x4 d, int sh, i32x4& a) {
#pragma unroll
    for (int r = 0; r < 4; r++) {
        int z = d[r];
        z = z > 1024 ? 1024 : z;                 // z >= 0 always
        int r4 = (z + 1 + ((z >> 2) & 1)) & ~3;
        a[r] += r4 << sh;
    }
}

// quantize one row spread over a 16-lane group (lane i16 holds k=36*i16..+35,
// k-ordered). Stats via 4-step shuffle (exact); 9 dword-aligned b32 writes,
// col = k + 12*chunk (i.e. chunk*128 + k%116).
__device__ __forceinline__ void quant36(const float (&v)[36], unsigned char* rowp,
                                        int i16, float* sc, float* of,
                                        float* sm_, int sidx)
{
    float mn = v[0], mx = v[0], sm = 0.f;
#pragma unroll
    for (int m = 0; m < 36; m++) { mn = fminf(mn, v[m]); mx = fmaxf(mx, v[m]); sm += v[m]; }
#pragma unroll
    for (int off = 1; off < 16; off <<= 1) {
        mn = fminf(mn, __shfl_xor(mn, off));
        mx = fmaxf(mx, __shfl_xor(mx, off));
        sm += __shfl_xor(sm, off);
    }
    float step = (mx - mn) / 255.0f;
    if (i16 == 0) { sc[sidx] = step; of[sidx] = mn; sm_[sidx] = sm; }
    int k0 = i16 * 36;
#pragma unroll
    for (int d = 0; d < 9; d++) {
        unsigned int dw = 0;
#pragma unroll
        for (int mb = 0; mb < 4; mb++) {
            int q = (int)rintf((v[d * 4 + mb] - mn) / step);
            q = q < 0 ? 0 : (q > 255 ? 255 : q);
            dw |= (unsigned)q << (8 * mb);
        }
        int kd = k0 + d * 4;
        int ch = kd / NPB;
        *(unsigned int*)(rowp + kd + 12 * ch) = dw;
    }
}

// zero the K-pad dwords of scratch row (idx>>4), pad dword (idx&15)
__device__ __forceinline__ void zero_pad_row(unsigned char* scr, int idx) {
    int rl = idx >> 4, dwp = idx & 15;
    int col = dwp < 12 ? (dwp / 3) * 128 + 116 + (dwp % 3) * 4
                       : 624 + (dwp - 12) * 4;
    *(unsigned int*)(scr + rl * SSTR + col) = 0u;
}

// copy 16-row scratch -> linear fragment tile (10,240 B) in global.
__device__ __forceinline__ void copy_out(const unsigned char* scr,
                                         unsigned char* dst, int tid) {
    for (int idx = tid; idx < 640; idx += 256) {
        int u = idx >> 4, rl = idx & 15;
        int dst16 = (u >> 3) * 128 + ((u >> 2) & 1) * 64 + (u & 3) * 16 + rl;
        *(i32x4*)(dst + dst16 * 16) = *(const i32x4*)(scr + rl * SSTR + u * 16);
    }
}

// ---------------- kernel 1: one-time quantization of x and w ----------------
__global__ __launch_bounds__(256) void k_q(
    const float* __restrict__ x, const float* __restrict__ w,
    unsigned char* __restrict__ Xq, unsigned char* __restrict__ Wq,
    float* __restrict__ xscg, float* __restrict__ xofg, float* __restrict__ xsmg,
    float* __restrict__ wscg, float* __restrict__ wofg, float* __restrict__ wsmg)
{
    __shared__ float xs2[64 * 57];                      // [cin][kh*18+c]
    __shared__ __align__(16) unsigned char scr[16 * SSTR];

    int tid = threadIdx.x, wv = tid >> 6, lane = tid & 63;
    int g = lane >> 4, i16 = lane & 15;
    int blk = blockIdx.x;

    if (blk < 392) {
        int b = blk >= 196 ? 1 : 0;
        int pos0 = (blk - 196 * b) * 16;
        const float* xb = x + (size_t)(b * 64) * 3136;
        for (int i = tid; i < 64 * 54; i += 256) {
            int cin = i / 54, rem = i - cin * 54;
            int kh = rem / 18;
            int gg = pos0 + (rem - kh * 18) - 1;
            float vv = 0.f;
            if (gg >= 0 && gg < 3136) {
                int hg = gg / 56, wg = gg - hg * 56;
                int r = hg - 1 + kh;
                if (r >= 0 && r < 56) vv = xb[cin * 3136 + r * 56 + wg];
            }
            xs2[cin * 57 + rem] = vv;
        }
        zero_pad_row(scr, tid);
        __syncthreads();

        int i = wv * 4 + g;               // tile-local row 0..15
        int pos = pos0 + i;
        int w_ = pos - (pos / 56) * 56;
        float v[36];
#pragma unroll
        for (int m = 0; m < 36; m++) {
            int r9 = m % 9, kh = r9 / 3, kw = r9 - kh * 3;
            int cin = i16 * 4 + m / 9;
            int ww = w_ - 1 + kw;
            v[m] = (ww >= 0 && ww < 56) ? xs2[cin * 57 + kh * 18 + i + kw] : 0.f;
        }
        quant36(v, scr + i * SSTR, i16, xscg, xofg, xsmg, blk * 16 + i);
        __syncthreads();

        copy_out(scr, Xq + (size_t)blk * 10240, tid);
    } else {
        int ctile = blk - 392;
        zero_pad_row(scr, tid);
        int rl = wv * 4 + g;              // 0..15
        int row = ctile * 16 + rl;
        const float* wr = w + (size_t)row * KDIM + i16 * 36;
        float v[36];
#pragma unroll
        for (int d = 0; d < 9; d++) {
            f32x4 t = *(const f32x4*)(wr + d * 4);
            v[d*4+0] = t[0]; v[d*4+1] = t[1]; v[d*4+2] = t[2]; v[d*4+3] = t[3];
        }
        quant36(v, scr + rl * SSTR, i16, wscg, wofg, wsmg, row);
        __syncthreads();

        copy_out(scr, Wq + (size_t)ctile * 10240, tid);
    }
}

// ---------------- kernel 2: crossbar MFMA + ADC + dequant (looped) ----------
__global__ __launch_bounds__(256) void k_d(
    const unsigned char* __restrict__ Xq, const unsigned char* __restrict__ Wq,
    const float* __restrict__ xscg, const float* __restrict__ xofg,
    const float* __restrict__ xsmg,
    const float* __restrict__ wscg, const float* __restrict__ wofg,
    const float* __restrict__ wsmg, float* __restrict__ out)
{
    __shared__ __align__(16) int pacc[2][64][4];

    int tid = threadIdx.x, wv = tid >> 6, lane = tid & 63;
    int g = lane >> 4, i16 = lane & 15;
    int blk = blockIdx.x;                 // 0..1567
    int ct = blk & 7, rp = blk >> 3;      // rp 0..195
    int tl = wv & 1, khalf = wv >> 1;
    int rtile = rp * 2 + tl;              // 0..391
    const unsigned char* xt = Xq + (size_t)rtile * 10240 + lane * 16;
    const unsigned char* wt = Wq + (size_t)ct * 10240 + lane * 16;

    i32x4 acc2[2] = {{0,0,0,0},{0,0,0,0}};
    const i32x4 zero = {0, 0, 0, 0};
    int cbeg = khalf ? 3 : 0, cend = khalf ? 5 : 3;

    // compact I$-resident main loop: ws unrolled x4, chunk & is looped
#pragma unroll 1
    for (int ch = cbeg; ch < cend; ++ch) {
        const unsigned char* xc = xt + ch * 2048;
        const unsigned char* wc = wt + ch * 2048;
        i32x4 x0 = *(const i32x4*)(xc), x1 = *(const i32x4*)(xc + 1024);
        i32x4 w0 = *(const i32x4*)(wc), w1 = *(const i32x4*)(wc + 1024);
        i32x4 wA0 = slice2b(w0, 6), wA1 = slice2b(w1, 6);
        i32x4 wB0 = slice2b(w0, 4), wB1 = slice2b(w1, 4);
        i32x4 wC0 = slice2b(w0, 2), wC1 = slice2b(w1, 2);
        i32x4 wD0 = slice2b(w0, 0), wD1 = slice2b(w1, 0);
#pragma unroll 1
        for (int is = 0; is < 4; ++is) {
            int ish = 6 - 2 * is;             // wave-uniform (SGPR shifts)
            i32x4 a0 = slice2b(x0, ish), a1 = slice2b(x1, ish);
            i32x4 d;
            d = __builtin_amdgcn_mfma_i32_16x16x64_i8(wA0, a0, zero, 0, 0, 0);
            d = __builtin_amdgcn_mfma_i32_16x16x64_i8(wA1, a1, d, 0, 0, 0);
            adc4(d, ish + 6, acc2[0]);
            d = __builtin_amdgcn_mfma_i32_16x16x64_i8(wB0, a0, zero, 0, 0, 0);
            d = __builtin_amdgcn_mfma_i32_16x16x64_i8(wB1, a1, d, 0, 0, 0);
            adc4(d, ish + 4, acc2[1]);
            d = __builtin_amdgcn_mfma_i32_16x16x64_i8(wC0, a0, zero, 0, 0, 0);
            d = __builtin_amdgcn_mfma_i32_16x16x64_i8(wC1, a1, d, 0, 0, 0);
            adc4(d, ish + 2, acc2[0]);
            d = __builtin_amdgcn_mfma_i32_16x16x64_i8(wD0, a0, zero, 0, 0, 0);
            d = __builtin_amdgcn_mfma_i32_16x16x64_i8(wD1, a1, d, 0, 0, 0);
            adc4(d, ish + 0, acc2[1]);
        }
    }

    i32x4 acc;
#pragma unroll
    for (int r = 0; r < 4; r++) acc[r] = acc2[0][r] + acc2[1][r];   // exact

    if (khalf == 0) *(i32x4*)&pacc[tl][lane][0] = acc;
    __syncthreads();

    if (khalf == 1) {
        i32x4 p = *(const i32x4*)&pacc[tl][lane][0];
#pragma unroll
        for (int r = 0; r < 4; r++) acc[r] += p[r];      // chunk-sum, exact

        // epilogue: D[row = w-row (g*4+r), col = x-row (i16)]; 64B coalesced
        int b = rtile >= 196 ? 1 : 0;
        int xrow = rtile * 16 + i16;
        float xs_ = xscg[xrow], xo = xofg[xrow], xsv = xsmg[xrow];
        int hw = (rtile - 196 * b) * 16 + i16;
#pragma unroll
        for (int r = 0; r < 4; r++) {
            int wrow = ct * 16 + g * 4 + r;
            float tt = ((float)acc[r] * xs_) * wscg[wrow];
            float res = ((tt + xo * wsmg[wrow]) + wofg[wrow] * xsv)
                      - (xo * wofg[wrow]) * 576.0f;
            out[(size_t)(b * 128 + wrow) * 3136 + hw] = res;
        }
    }
}

extern "C" void kernel_launch(void* const* d_in, const int* in_sizes, int n_in,
                              void* d_out, int out_size, void* d_ws, size_t ws_size,
                              hipStream_t stream) {
    const float* x = (const float*)d_in[0];   // [2][64][56][56]
    const float* w = (const float*)d_in[1];   // [128][64][3][3]
    float* out = (float*)d_out;               // [2][128][56][56]

    unsigned char* Xq = (unsigned char*)d_ws;          // 392*10,240 = 4,014,080 B
    unsigned char* Wq = Xq + (size_t)392 * 10240;      // 8*10,240   = 81,920 B
    float* xsc = (float*)(Wq + 8 * 10240);
    float* xof = xsc + 6272;
    float* xsm = xof + 6272;
    float* wsc = xsm + 6272;
    float* wof = wsc + 128;
    float* wsm = wof + 128;

    hipLaunchKernelGGL(k_q, dim3(400), dim3(256), 0, stream,
                       x, w, Xq, Wq, xsc, xof, xsm, wsc, wof, wsm);
    hipLaunchKernelGGL(k_d, dim3(1568), dim3(256), 0, stream,
                       Xq, Wq, xsc, xof, xsm, wsc, wof, wsm, out);
}